// Round 17
// baseline (16422.495 us; speedup 1.0000x reference)
//
#include <hip/hip_runtime.h>
#include <hip/hip_cooperative_groups.h>

#define B_ 64
#define H_ 1024
#define IN_ 512
#define S_ 256
#define L_ 6
#define NG_ 4096
#define NTASK 768            // 6 cells * 128 col-slices (8 H-cols x 4 gates)
#define NTICK (S_ + L_ - 1)

typedef __bf16 bf16x8 __attribute__((ext_vector_type(8)));
typedef float f32x4 __attribute__((ext_vector_type(4)));
typedef int v4i __attribute__((ext_vector_type(4)));
typedef unsigned short ushort8v __attribute__((ext_vector_type(8)));
typedef unsigned short ushort_t;
typedef signed char i8_t;

// ws: Wp8 panels 48MB | xb 16MB | hbf 768KB
#define WP8_BYTES 50331648ul
#define XB_BYTES 16777216ul
#define HB8_BYTES 786432ul
#define XSLOT_SH 32768ul          // shorts per x timestep slot
#define HLAYER 65536ul            // bytes per layer h (64x1024 i8)

#define QW 4064.0f                        // 127 / 0.03125
#define SCL (0.03125f / 16129.0f)         // step_w * step_h

#define MFMA_BF16(a,b,c) __builtin_amdgcn_mfma_f32_16x16x32_bf16(a,b,c,0,0,0)
#define MFMA_I8(a,b,c)   __builtin_amdgcn_mfma_i32_16x16x64_i8(a,b,c,0,0,0)

__device__ __forceinline__ unsigned short f2bf(float f) {
  union { float f; unsigned u; } v; v.f = f;
  unsigned r = v.u + 0x7fffu + ((v.u >> 16) & 1u);
  return (unsigned short)(r >> 16);
}
__device__ __forceinline__ i8_t q8w(float w) {
  float q = rintf(w * QW);
  q = fminf(127.f, fmaxf(-127.f, q));
  return (i8_t)(int)q;
}

// ---- one-time weight pack to i8 panels (+bf16 U0 for layer 0) ----
// panel(l,jb) 64KB: [U 32KB][V 32KB].
// i8 unit (c*2+nf) 1KB: lane(l15,kg), e: k=c*64+kg*16+e,
//   n=(nf*2+(l15>>3))*1024+jb*8+(l15&7)  [same n-map proven in R11-R16]
// l==0 U region: bf16 units (c32*2+nf) 1KB: k=c32*32+kg*8+e (8 bf16/lane)
__global__ void k_pack_w8(const float* __restrict__ U0, const float* __restrict__ V0,
                          const float* __restrict__ U, const float* __restrict__ V,
                          i8_t* __restrict__ Wp) {
  const int bx = blockIdx.x;              // 0..767
  const int l = bx >> 7, jb = bx & 127;
  i8_t* __restrict__ panel = Wp + (size_t)bx * 65536ul;
  const int tid = threadIdx.x, lane = tid & 63, g4 = tid >> 6;
  const int l15 = lane & 15, kg = lane >> 4;
  const float* __restrict__ Vsrc = (l == 0) ? V0 : V + (size_t)(l - 1) * H_ * NG_;
  // V part (i8, 32 units)
  for (int p = 0; p < 8; ++p) {
    const int gi = p * 4 + g4;
    const int cv = gi >> 1, nf = gi & 1;
    const int n = (nf * 2 + (l15 >> 3)) * 1024 + jb * 8 + (l15 & 7);
    const int k0 = cv * 64 + kg * 16;
    i8_t qb[16];
#pragma unroll
    for (int e = 0; e < 16; ++e) qb[e] = q8w(Vsrc[(size_t)(k0 + e) * NG_ + n]);
    *(v4i*)(panel + 32768 + (size_t)gi * 1024 + lane * 16) = *(const v4i*)qb;
  }
  if (l == 0) {
    ushort_t* p16 = (ushort_t*)panel;
    for (int p = 0; p < 8; ++p) {
      const int gi = p * 4 + g4;
      const int c32 = gi >> 1, nf = gi & 1;
      const int n = (nf * 2 + (l15 >> 3)) * 1024 + jb * 8 + (l15 & 7);
      const int k0 = c32 * 32 + kg * 8;
      ushort8v u;
#pragma unroll
      for (int e = 0; e < 8; ++e) u[e] = f2bf(U0[(size_t)(k0 + e) * NG_ + n]);
      *(ushort8v*)(p16 + (size_t)gi * 512 + lane * 8) = u;
    }
  } else {
    const float* __restrict__ Usrc = U + (size_t)(l - 1) * H_ * NG_;
    for (int p = 0; p < 8; ++p) {
      const int gi = p * 4 + g4;
      const int cu = gi >> 1, nf = gi & 1;
      const int n = (nf * 2 + (l15 >> 3)) * 1024 + jb * 8 + (l15 & 7);
      const int k0 = cu * 64 + kg * 16;
      i8_t qb[16];
#pragma unroll
      for (int e = 0; e < 16; ++e) qb[e] = q8w(Usrc[(size_t)(k0 + e) * NG_ + n]);
      *(v4i*)(panel + (size_t)gi * 1024 + lane * 16) = *(const v4i*)qb;
    }
  }
}

// ---- one-time x -> bf16 A-frags: unit u = c32*4 + m; row=m*16+l15, k=c32*32+kg*8+e
__global__ void k_cvt_x(const float* __restrict__ x, ushort_t* __restrict__ xb) {
  const int t = blockIdx.x, tid = threadIdx.x;
  const int lane = tid & 63, g4 = tid >> 6;
  const int l15 = lane & 15, kg = lane >> 4;
  ushort_t* __restrict__ dst = xb + (size_t)t * XSLOT_SH;
  for (int u = g4; u < 64; u += 4) {
    const int c32 = u >> 2, m = u & 3;
    const int row = m * 16 + l15, k = c32 * 32 + kg * 8;
    const float* __restrict__ src = x + ((size_t)row * S_ + t) * IN_ + k;
    float4 v0 = *(const float4*)src;
    float4 v1 = *(const float4*)(src + 4);
    ushort8v uv = { f2bf(v0.x), f2bf(v0.y), f2bf(v0.z), f2bf(v0.w),
                    f2bf(v1.x), f2bf(v1.y), f2bf(v1.z), f2bf(v1.w) };
    *(ushort8v*)(dst + (size_t)u * 512 + lane * 8) = uv;
  }
}

// ---- per-wave cell GEMMs (wave owns rows w*16..+15, 32 N-cols) ----
template<bool PERS>
__device__ __forceinline__ void cell_lx(int w, int lane,
                                        const i8_t* __restrict__ A1,
                                        const i8_t* __restrict__ A2,
                                        const i8_t* __restrict__ gpanel,
                                        const i8_t* sW, v4i aU[2], v4i aV[2]) {
#pragma unroll
  for (int cu = 8; cu < 16; ++cu) {      // streamed U half (loads issue first)
    v4i a = *(const v4i*)(A1 + (size_t)((cu * 4 + w) << 10) + lane * 16);
    v4i w0 = *(const v4i*)(gpanel + (size_t)cu * 2048 + lane * 16);
    v4i w1 = *(const v4i*)(gpanel + (size_t)cu * 2048 + 1024 + lane * 16);
    aU[0] = MFMA_I8(a, w0, aU[0]);
    aU[1] = MFMA_I8(a, w1, aU[1]);
  }
#pragma unroll
  for (int cu = 0; cu < 8; ++cu) {       // persisted U half
    v4i a = *(const v4i*)(A1 + (size_t)((cu * 4 + w) << 10) + lane * 16);
    const i8_t* wb = PERS ? (sW + cu * 2048 + lane * 16)
                          : (gpanel + (size_t)cu * 2048 + lane * 16);
    v4i w0 = *(const v4i*)wb;
    v4i w1 = *(const v4i*)(wb + 1024);
    aU[0] = MFMA_I8(a, w0, aU[0]);
    aU[1] = MFMA_I8(a, w1, aU[1]);
  }
#pragma unroll
  for (int cv = 0; cv < 16; ++cv) {      // persisted V
    v4i a = *(const v4i*)(A2 + (size_t)((cv * 4 + w) << 10) + lane * 16);
    const i8_t* wb = PERS ? (sW + 16384 + cv * 2048 + lane * 16)
                          : (gpanel + 32768 + (size_t)cv * 2048 + lane * 16);
    v4i w0 = *(const v4i*)wb;
    v4i w1 = *(const v4i*)(wb + 1024);
    aV[0] = MFMA_I8(a, w0, aV[0]);
    aV[1] = MFMA_I8(a, w1, aV[1]);
  }
}

template<bool PERS>
__device__ __forceinline__ void cell_l0(int w, int lane,
                                        const ushort_t* __restrict__ X,
                                        const i8_t* __restrict__ A2,
                                        const i8_t* __restrict__ gpanel,
                                        const i8_t* sW, f32x4 fU[2], v4i aV[2]) {
  const ushort_t* gp16 = (const ushort_t*)gpanel;
#pragma unroll
  for (int c = 8; c < 16; ++c) {         // streamed U0 half (bf16)
    bf16x8 a = *(const bf16x8*)(X + (size_t)(c * 4 + w) * 512 + lane * 8);
    bf16x8 w0 = *(const bf16x8*)(gp16 + (size_t)(c * 2) * 512 + lane * 8);
    bf16x8 w1 = *(const bf16x8*)(gp16 + (size_t)(c * 2 + 1) * 512 + lane * 8);
    fU[0] = MFMA_BF16(a, w0, fU[0]);
    fU[1] = MFMA_BF16(a, w1, fU[1]);
  }
#pragma unroll
  for (int c = 0; c < 8; ++c) {          // persisted U0 half
    bf16x8 a = *(const bf16x8*)(X + (size_t)(c * 4 + w) * 512 + lane * 8);
    const ushort_t* wb = PERS ? ((const ushort_t*)sW + c * 1024 + lane * 8)
                              : (gp16 + (size_t)c * 1024 + lane * 8);
    bf16x8 w0 = *(const bf16x8*)wb;
    bf16x8 w1 = *(const bf16x8*)(wb + 512);
    fU[0] = MFMA_BF16(a, w0, fU[0]);
    fU[1] = MFMA_BF16(a, w1, fU[1]);
  }
#pragma unroll
  for (int cv = 0; cv < 16; ++cv) {      // persisted V (i8)
    v4i a = *(const v4i*)(A2 + (size_t)((cv * 4 + w) << 10) + lane * 16);
    const i8_t* wb = PERS ? (sW + 16384 + cv * 2048 + lane * 16)
                          : (gpanel + 32768 + (size_t)cv * 2048 + lane * 16);
    v4i w0 = *(const v4i*)wb;
    v4i w1 = *(const v4i*)(wb + 1024);
    aV[0] = MFMA_I8(a, w0, aV[0]);
    aV[1] = MFMA_I8(a, w1, aV[1]);
  }
}

// ---- primary: persistent-task kernel (nwg == 768), weights LDS-resident ----
__global__ void __launch_bounds__(256, 3)
k_lstm_p(const ushort_t* __restrict__ xb, const i8_t* __restrict__ Wp,
         const float* __restrict__ b0, const float* __restrict__ bL,
         i8_t* __restrict__ hbf, float* __restrict__ out) {
  cooperative_groups::grid_group grid = cooperative_groups::this_grid();
  float* __restrict__ seq = out;
  float* __restrict__ hf = out + (size_t)B_ * S_ * H_;
  float* __restrict__ cf = hf + (size_t)L_ * B_ * H_;
  __shared__ __align__(16) i8_t sW[49152];
  __shared__ __align__(8) i8_t hst[512];

  const int tid = threadIdx.x, w = tid >> 6, lane = tid & 63;
  const int l15 = lane & 15, kg = lane >> 4;
  const bool lo = (l15 < 8);
  const int wg = blockIdx.x;
  const int l = wg >> 7, jb = wg & 127;
  const i8_t* __restrict__ gpanel = Wp + (size_t)wg * 65536ul;

  { // one-time persist: U first-half + all V
    int* d0 = (int*)sW;
    const int* s0 = (const int*)gpanel;
    for (int i = tid; i < 4096; i += 256) d0[i] = s0[i];
    int* d1 = (int*)(sW + 16384);
    const int* s1 = (const int*)(gpanel + 32768);
    for (int i = tid; i < 8192; i += 256) d1[i] = s1[i];
  }
  __syncthreads();

  const int hc = (jb << 3) + (l15 & 7);
  const float* __restrict__ bias = (l == 0) ? b0 : (bL + (size_t)(l - 1) * NG_);
  const float bi = bias[hc], bfv = bias[1024 + hc];
  const float bgv = bias[2048 + hc], bov = bias[3072 + hc];
  float creg[4] = {0.f, 0.f, 0.f, 0.f};

  for (int T = 0; T < NTICK; ++T) {
    const int t = T - l;
    if (t >= 0 && t < S_) {
      const i8_t* __restrict__ hprev = hbf + (size_t)((T + 1) & 1) * (L_ * HLAYER);
      i8_t* __restrict__ hcur = hbf + (size_t)(T & 1) * (L_ * HLAYER) + (size_t)l * HLAYER;
      const i8_t* __restrict__ A2 = hprev + (size_t)l * HLAYER;

      v4i aV[2] = {{0,0,0,0},{0,0,0,0}};
      float z0[4], z1[4];
      if (l == 0) {
        f32x4 fU[2] = {{0,0,0,0},{0,0,0,0}};
        cell_l0<true>(w, lane, xb + (size_t)t * XSLOT_SH, A2, gpanel, sW, fU, aV);
#pragma unroll
        for (int j = 0; j < 4; ++j) {
          z0[j] = fU[0][j] + (float)aV[0][j] * SCL;
          z1[j] = fU[1][j] + (float)aV[1][j] * SCL;
        }
      } else {
        v4i aU[2] = {{0,0,0,0},{0,0,0,0}};
        cell_lx<true>(w, lane, hprev + (size_t)(l - 1) * HLAYER, A2, gpanel, sW, aU, aV);
#pragma unroll
        for (int j = 0; j < 4; ++j) {
          z0[j] = (float)(aU[0][j] + aV[0][j]) * SCL;
          z1[j] = (float)(aU[1][j] + aV[1][j]) * SCL;
        }
      }

#pragma unroll
      for (int j = 0; j < 4; ++j) {
        float p0 = __shfl_xor(z0[j], 8, 64);
        float p1 = __shfl_xor(z1[j], 8, 64);
        float zi = (lo ? z0[j] : p0) + bi;
        float zf = (lo ? p0 : z0[j]) + bfv;
        float zg = (lo ? z1[j] : p1) + bgv;
        float zo = (lo ? p1 : z1[j]) + bov;
        float iv = 1.f / (1.f + expf(-zi));
        float fv = 1.f / (1.f + expf(-zf));
        float gv = tanhf(zg);
        float ov = 1.f / (1.f + expf(-zo));
        float cn = fv * creg[j] + iv * gv;
        creg[j] = cn;
        float hv = ov * tanhf(cn);
        const int r = w * 16 + kg * 4 + j;
        if (lo) {
          hst[r * 8 + (l15 & 7)] = (i8_t)(int)rintf(hv * 127.f);
          if (l == L_ - 1) seq[((size_t)r * S_ + t) * H_ + hc] = hv;
          if (t == S_ - 1) {
            cf[((size_t)l * B_ + r) * H_ + hc] = cn;
            hf[((size_t)l * B_ + r) * H_ + hc] = hv;
          }
        }
      }
      __syncthreads();
      if (tid < 64) {   // h write: 8 bytes/row into packed i8 A-unit layout
        const int row = tid, m = row >> 4, r15 = row & 15;
        unsigned long long v = *(const unsigned long long*)(hst + row * 8);
        const int c = jb >> 3;
        const int kgh = ((jb & 7) * 8) >> 4;
        const int e0 = (jb * 8) & 15;
        *(unsigned long long*)(hcur + (size_t)((c * 4 + m) << 10) +
                               (kgh * 16 + r15) * 16 + e0) = v;
      }
      __syncthreads();
    }
    grid.sync();
  }
}

// ---- fallback: multi-task kernel (any nwg), all weights from global ----
__global__ void __launch_bounds__(256)
k_lstm_g(const ushort_t* __restrict__ xb, const i8_t* __restrict__ Wp,
         const float* __restrict__ b0, const float* __restrict__ bL,
         i8_t* __restrict__ hbf, float* __restrict__ out) {
  cooperative_groups::grid_group grid = cooperative_groups::this_grid();
  float* __restrict__ seq = out;
  float* __restrict__ hf = out + (size_t)B_ * S_ * H_;
  float* __restrict__ cf = hf + (size_t)L_ * B_ * H_;
  __shared__ __align__(8) i8_t hst[512];

  const int tid = threadIdx.x, w = tid >> 6, lane = tid & 63;
  const int l15 = lane & 15, kg = lane >> 4;
  const bool lo = (l15 < 8);
  const int wg = blockIdx.x, nwg = gridDim.x;

  for (int T = 0; T < NTICK; ++T) {
    for (int task = wg; task < NTASK; task += nwg) {
      const int l = task >> 7, jb = task & 127;
      const int t = T - l;
      if (t < 0 || t >= S_) continue;
      const i8_t* __restrict__ hprev = hbf + (size_t)((T + 1) & 1) * (L_ * HLAYER);
      i8_t* __restrict__ hcur = hbf + (size_t)(T & 1) * (L_ * HLAYER) + (size_t)l * HLAYER;
      const i8_t* __restrict__ gpanel = Wp + (size_t)task * 65536ul;
      const i8_t* __restrict__ A2 = hprev + (size_t)l * HLAYER;

      v4i aV[2] = {{0,0,0,0},{0,0,0,0}};
      float z0[4], z1[4];
      if (l == 0) {
        f32x4 fU[2] = {{0,0,0,0},{0,0,0,0}};
        cell_l0<false>(w, lane, xb + (size_t)t * XSLOT_SH, A2, gpanel, nullptr, fU, aV);
#pragma unroll
        for (int j = 0; j < 4; ++j) {
          z0[j] = fU[0][j] + (float)aV[0][j] * SCL;
          z1[j] = fU[1][j] + (float)aV[1][j] * SCL;
        }
      } else {
        v4i aU[2] = {{0,0,0,0},{0,0,0,0}};
        cell_lx<false>(w, lane, hprev + (size_t)(l - 1) * HLAYER, A2, gpanel, nullptr, aU, aV);
#pragma unroll
        for (int j = 0; j < 4; ++j) {
          z0[j] = (float)(aU[0][j] + aV[0][j]) * SCL;
          z1[j] = (float)(aU[1][j] + aV[1][j]) * SCL;
        }
      }

      const int hc = (jb << 3) + (l15 & 7);
      const float* __restrict__ bias = (l == 0) ? b0 : (bL + (size_t)(l - 1) * NG_);
      const float bi = bias[hc], bfv = bias[1024 + hc];
      const float bgv = bias[2048 + hc], bov = bias[3072 + hc];
#pragma unroll
      for (int j = 0; j < 4; ++j) {
        float p0 = __shfl_xor(z0[j], 8, 64);
        float p1 = __shfl_xor(z1[j], 8, 64);
        float zi = (lo ? z0[j] : p0) + bi;
        float zf = (lo ? p0 : z0[j]) + bfv;
        float zg = (lo ? z1[j] : p1) + bgv;
        float zo = (lo ? p1 : z1[j]) + bov;
        float iv = 1.f / (1.f + expf(-zi));
        float fv = 1.f / (1.f + expf(-zf));
        float gv = tanhf(zg);
        float ov = 1.f / (1.f + expf(-zo));
        const int r = w * 16 + kg * 4 + j;
        float cold = (t > 0) ? cf[((size_t)l * B_ + r) * H_ + hc] : 0.f;
        float cn = fv * cold + iv * gv;
        float hv = ov * tanhf(cn);
        if (lo) {
          hst[r * 8 + (l15 & 7)] = (i8_t)(int)rintf(hv * 127.f);
          cf[((size_t)l * B_ + r) * H_ + hc] = cn;
          if (t == S_ - 1) hf[((size_t)l * B_ + r) * H_ + hc] = hv;
          if (l == L_ - 1) seq[((size_t)r * S_ + t) * H_ + hc] = hv;
        }
      }
      __syncthreads();
      if (tid < 64) {
        const int row = tid, m = row >> 4, r15 = row & 15;
        unsigned long long v = *(const unsigned long long*)(hst + row * 8);
        const int c = jb >> 3;
        const int kgh = ((jb & 7) * 8) >> 4;
        const int e0 = (jb * 8) & 15;
        *(unsigned long long*)(hcur + (size_t)((c * 4 + m) << 10) +
                               (kgh * 16 + r15) * 16 + e0) = v;
      }
      __syncthreads();
    }
    grid.sync();
  }
}

extern "C" void kernel_launch(void* const* d_in, const int* in_sizes, int n_in,
                              void* d_out, int out_size, void* d_ws, size_t ws_size,
                              hipStream_t stream) {
  const float* x = (const float*)d_in[0];
  const float* U0 = (const float*)d_in[1];
  const float* V0 = (const float*)d_in[2];
  const float* b0 = (const float*)d_in[3];
  const float* U = (const float*)d_in[4];
  const float* V = (const float*)d_in[5];
  const float* bL = (const float*)d_in[6];
  float* out = (float*)d_out;

  char* ws = (char*)d_ws;
  i8_t* Wp = (i8_t*)ws;
  ushort_t* xb = (ushort_t*)(ws + WP8_BYTES);
  i8_t* hbf = (i8_t*)(ws + WP8_BYTES + XB_BYTES);

  hipLaunchKernelGGL(k_pack_w8, dim3(NTASK), dim3(256), 0, stream, U0, V0, U, V, Wp);
  hipLaunchKernelGGL(k_cvt_x, dim3(S_), dim3(256), 0, stream, x, xb);
  hipMemsetAsync(hbf, 0, HB8_BYTES, stream);

  int maxB = 0;
  hipOccupancyMaxActiveBlocksPerMultiprocessor(&maxB, k_lstm_p, 256, 0);
  if (maxB >= 3) {
    void* args[] = { (void*)&xb, (void*)&Wp, (void*)&b0, (void*)&bL,
                     (void*)&hbf, (void*)&out };
    hipError_t e = hipLaunchCooperativeKernel((void*)k_lstm_p, dim3(NTASK),
                                              dim3(256), args, 0, stream);
    if (e == hipSuccess) return;
    (void)hipGetLastError();
  }
  int maxG = 0;
  hipOccupancyMaxActiveBlocksPerMultiprocessor(&maxG, k_lstm_g, 256, 0);
  int nwg = maxG * 256;
  if (nwg > NTASK) nwg = NTASK;
  if (nwg < 64) nwg = 256;
  void* args2[] = { (void*)&xb, (void*)&Wp, (void*)&b0, (void*)&bL,
                    (void*)&hbf, (void*)&out };
  hipLaunchCooperativeKernel((void*)k_lstm_g, dim3(nwg), dim3(256),
                             args2, 0, stream);
}